// Round 10
// baseline (45397.894 us; speedup 1.0000x reference)
//
#include <hip/hip_runtime.h>
#include <hip/hip_bf16.h>

#define T_STEPS 4096
#define HID 128
#define INP 8
#define MID 50
#define KSUB 10

typedef float v2f __attribute__((ext_vector_type(2)));

__device__ __forceinline__ v2f mk2(float a, float b){ v2f r; r.x = a; r.y = b; return r; }
__device__ __forceinline__ v2f bc2(float s){ v2f r; r.x = s; r.y = s; return r; }

__device__ __forceinline__ v2f fma2(v2f a, v2f b, v2f c){
#if __has_builtin(__builtin_elementwise_fma)
    return __builtin_elementwise_fma(a, b, c);
#else
    c.x = fmaf(a.x, b.x, c.x); c.y = fmaf(a.y, b.y, c.y); return c;
#endif
}

__device__ __forceinline__ float rlane(float v, int i){
    return __int_as_float(__builtin_amdgcn_readlane(__float_as_int(v), i));
}

__device__ __forceinline__ float fast_tanh(float x){
    float e = __expf(2.0f * x);
    return 1.0f - 2.0f / (e + 1.0f);
}
__device__ __forceinline__ float softplus_f(float x){
    return (x > 20.0f) ? x : __logf(1.0f + __expf(x));
}

// lgkmcnt-only barrier: orders LDS ops, lets global loads stay in flight.
__device__ __forceinline__ void wg_barrier(){
    asm volatile("s_waitcnt lgkmcnt(0)\n\ts_barrier" ::: "memory");
}

// 6 waves:
//   waves 0-3: recurrence, 4-way K-split, z register-resident (lane l holds
//     z[32w + (l&31)]). Phase A: 32 readlane + 16 pk-FMA -> partial -> pbuf,
//     ONE barrier, 4 b32 reads -> h1[l] in register. Phase B: 50 readlane +
//     25 pk-FMA (K-packed). setprio(1) so heads never steal issue slots.
//   waves 4-5: sigma/mu heads, lag 1 step, CHUNKED across the 10 substep
//     barriers (8x4 dot-iters + reduce + store) so head compute overlaps the
//     recurrence instead of sitting on the critical path between steps.
__global__ __launch_bounds__(384, 2)
void lode_kernel(const float* __restrict__ x, const float* __restrict__ dt,
                 const float* __restrict__ W1, const float* __restrict__ b1,
                 const float* __restrict__ W2, const float* __restrict__ b2,
                 const float* __restrict__ Wls1, const float* __restrict__ bls1,
                 const float* __restrict__ wls2, const float* __restrict__ bls2,
                 const float* __restrict__ Wlm1, const float* __restrict__ blm1,
                 float* __restrict__ out)
{
    __shared__ __align__(16) float pbuf[2][4][64];  // [dbuf][wave][lane] partials
    __shared__ __align__(16) float zsnap[2][HID];   // per-step snapshot for heads

    const int tid = threadIdx.x;
    const int wid = tid >> 6;
    const int l   = tid & 63;

    if (wid < 4){
        // ================= recurrence waves =================
        __builtin_amdgcn_s_setprio(1);          // win issue arbitration vs heads
        const int base = wid << 5;              // z quarter start
        const int lc   = (l < MID) ? l : 0;     // clamped h1-output index

        // phase A weights: pairs (W1[base+2i][lc], W1[base+2i+1][lc])
        v2f w1h[16];
        #pragma unroll
        for (int i = 0; i < 16; ++i){
            const float a = W1[(base + 2*i    )*MID + lc];
            const float b = W1[(base + 2*i + 1)*MID + lc];
            w1h[i] = (l < MID) ? mk2(a, b) : bc2(0.0f);
        }
        // x-part + bias: folded into wave 0's partial only
        float w1x[INP];
        #pragma unroll
        for (int j = 0; j < INP; ++j){
            const float v = W1[(HID + j)*MID + lc];
            w1x[j] = (wid == 0 && l < MID) ? v : 0.0f;
        }
        const float b1c = (wid == 0 && l < MID) ? b1[lc] : 0.0f;

        // phase B weights: K-pairs of column W2[k][jc]
        const int jc = base + (l & 31);
        v2f w2c[25];
        #pragma unroll
        for (int q = 0; q < 25; ++q)
            w2c[q] = mk2(W2[(2*q)*HID + jc], W2[(2*q + 1)*HID + jc]);
        const float b2c = b2[jc];

        float zj = 0.0f;                         // z[jc]

        float4 xa  = *reinterpret_cast<const float4*>(&x[0]);
        float4 xb  = *reinterpret_cast<const float4*>(&x[4]);
        float2 dtc = *reinterpret_cast<const float2*>(&dt[0]);

        for (int t = 0; t < T_STEPS; ++t){
            const int tn = (t + 1 < T_STEPS) ? t + 1 : t;
            const float4 xan = *reinterpret_cast<const float4*>(&x[tn*INP]);
            const float4 xbn = *reinterpret_cast<const float4*>(&x[tn*INP + 4]);
            const float2 dtn = *reinterpret_cast<const float2*>(&dt[2*tn]);

            float xacc = b1c;                    // nonzero on wave 0 only
            xacc = fmaf(xa.x, w1x[0], xacc); xacc = fmaf(xa.y, w1x[1], xacc);
            xacc = fmaf(xa.z, w1x[2], xacc); xacc = fmaf(xa.w, w1x[3], xacc);
            xacc = fmaf(xb.x, w1x[4], xacc); xacc = fmaf(xb.y, w1x[5], xacc);
            xacc = fmaf(xb.z, w1x[6], xacc); xacc = fmaf(xb.w, w1x[7], xacc);
            const float hstep = (dtc.y - dtc.x) * (1.0f / KSUB);

            #pragma unroll 2
            for (int s = 0; s < KSUB; ++s){
                // ---- phase A: own-quarter dot, z-pairs -> pk-FMA ----
                v2f A0 = mk2(xacc, 0.0f), A1 = bc2(0.0f), A2 = bc2(0.0f), A3 = bc2(0.0f);
                #pragma unroll
                for (int i = 0; i < 16; i += 4){
                    A0 = fma2(mk2(rlane(zj, 2*i+0), rlane(zj, 2*i+1)), w1h[i+0], A0);
                    A1 = fma2(mk2(rlane(zj, 2*i+2), rlane(zj, 2*i+3)), w1h[i+1], A1);
                    A2 = fma2(mk2(rlane(zj, 2*i+4), rlane(zj, 2*i+5)), w1h[i+2], A2);
                    A3 = fma2(mk2(rlane(zj, 2*i+6), rlane(zj, 2*i+7)), w1h[i+3], A3);
                }
                const v2f AA = (A0 + A1) + (A2 + A3);
                pbuf[s & 1][wid][l] = AA.x + AA.y;
                wg_barrier();                   // the substep's ONE barrier

                // ---- combine: lane l -> h1[l] ----
                const float p0 = pbuf[s & 1][0][l];
                const float p1 = pbuf[s & 1][1][l];
                const float p2 = pbuf[s & 1][2][l];
                const float p3 = pbuf[s & 1][3][l];
                const float h1v = fast_tanh((p0 + p1) + (p2 + p3)); // 0 for l>=50

                // ---- phase B: 50-dot, h1-pairs -> pk-FMA ----
                v2f D0 = bc2(0.0f), D1 = bc2(0.0f), D2 = bc2(0.0f), D3 = bc2(0.0f);
                #pragma unroll
                for (int q = 0; q < 24; q += 4){
                    D0 = fma2(mk2(rlane(h1v, 2*q+0), rlane(h1v, 2*q+1)), w2c[q+0], D0);
                    D1 = fma2(mk2(rlane(h1v, 2*q+2), rlane(h1v, 2*q+3)), w2c[q+1], D1);
                    D2 = fma2(mk2(rlane(h1v, 2*q+4), rlane(h1v, 2*q+5)), w2c[q+2], D2);
                    D3 = fma2(mk2(rlane(h1v, 2*q+6), rlane(h1v, 2*q+7)), w2c[q+3], D3);
                }
                D0 = fma2(mk2(rlane(h1v, 48), rlane(h1v, 49)), w2c[24], D0);
                const v2f DD = (D0 + D1) + (D2 + D3);
                zj += hstep * fast_tanh(b2c + DD.x + DD.y);
            }

            if (l < 32) zsnap[t & 1][base + l] = zj;   // publish for heads

            xa = xan; xb = xbn; dtc = dtn;
        }
        wg_barrier();                           // tail: publish step T-1 snapshot
    } else {
        // ============ head waves (4 = sigma, 5 = mu), lag 1, chunked ============
        const float* __restrict__ Wh = (wid == 4) ? Wls1 : Wlm1;
        const float* __restrict__ bh = (wid == 4) ? bls1 : blm1;
        float2 bhp;   bhp.x = bh[2*l];     bhp.y = bh[2*l+1];
        float2 wls2p; wls2p.x = wls2[2*l]; wls2p.y = wls2[2*l+1];
        const float bls2s = bls2[0];

        for (int t = 0; t < T_STEPS; ++t){
            float px = bhp.x, py = bhp.y;
            float r = 0.0f;
            const float* zs = &zsnap[(t - 1) & 1][0];
            #pragma unroll
            for (int s = 0; s < KSUB; ++s){
                wg_barrier();
                if (t == 0) continue;
                if (s < 8){
                    // 4 dot-iterations (k = 16s .. 16s+15)
                    #pragma unroll
                    for (int it = 0; it < 4; ++it){
                        const int k = 16*s + 4*it;
                        const float4 zv = *reinterpret_cast<const float4*>(&zs[k]);
                        const float2 a0 = *reinterpret_cast<const float2*>(&Wh[(k+0)*HID + 2*l]);
                        const float2 a1 = *reinterpret_cast<const float2*>(&Wh[(k+1)*HID + 2*l]);
                        const float2 a2 = *reinterpret_cast<const float2*>(&Wh[(k+2)*HID + 2*l]);
                        const float2 a3 = *reinterpret_cast<const float2*>(&Wh[(k+3)*HID + 2*l]);
                        px = fmaf(zv.x, a0.x, px); py = fmaf(zv.x, a0.y, py);
                        px = fmaf(zv.y, a1.x, px); py = fmaf(zv.y, a1.y, py);
                        px = fmaf(zv.z, a2.x, px); py = fmaf(zv.z, a2.y, py);
                        px = fmaf(zv.w, a3.x, px); py = fmaf(zv.w, a3.y, py);
                    }
                } else if (s == 8){
                    px = fast_tanh(px); py = fast_tanh(py);
                    r = px*wls2p.x + py*wls2p.y;
                    #pragma unroll
                    for (int off = 1; off < 64; off <<= 1) r += __shfl_xor(r, off, 64);
                } else {
                    if (l == 0){
                        const int ts = t - 1;
                        if (wid == 4) out[T_STEPS + ts] = softplus_f(r + bls2s);
                        else          out[ts]           = r + bls2s;
                    }
                }
            }
        }
        wg_barrier();                           // matches recurrence tail barrier

        // final head for step T-1 (recurrence has exited; no contention)
        {
            const int ts = T_STEPS - 1;
            const float* zs = &zsnap[ts & 1][0];
            float px = bhp.x, py = bhp.y;
            #pragma unroll 4
            for (int k = 0; k < HID; k += 4){
                const float4 zv = *reinterpret_cast<const float4*>(&zs[k]);
                const float2 a0 = *reinterpret_cast<const float2*>(&Wh[(k+0)*HID + 2*l]);
                const float2 a1 = *reinterpret_cast<const float2*>(&Wh[(k+1)*HID + 2*l]);
                const float2 a2 = *reinterpret_cast<const float2*>(&Wh[(k+2)*HID + 2*l]);
                const float2 a3 = *reinterpret_cast<const float2*>(&Wh[(k+3)*HID + 2*l]);
                px = fmaf(zv.x, a0.x, px); py = fmaf(zv.x, a0.y, py);
                px = fmaf(zv.y, a1.x, px); py = fmaf(zv.y, a1.y, py);
                px = fmaf(zv.z, a2.x, px); py = fmaf(zv.z, a2.y, py);
                px = fmaf(zv.w, a3.x, px); py = fmaf(zv.w, a3.y, py);
            }
            px = fast_tanh(px); py = fast_tanh(py);
            float r = px*wls2p.x + py*wls2p.y;
            #pragma unroll
            for (int off = 1; off < 64; off <<= 1) r += __shfl_xor(r, off, 64);
            if (l == 0){
                if (wid == 4) out[T_STEPS + ts] = softplus_f(r + bls2s);
                else          out[ts]           = r + bls2s;
            }
        }
    }
}

extern "C" void kernel_launch(void* const* d_in, const int* in_sizes, int n_in,
                              void* d_out, int out_size, void* d_ws, size_t ws_size,
                              hipStream_t stream)
{
    const float* x    = (const float*)d_in[0];
    const float* dt   = (const float*)d_in[1];
    const float* W1   = (const float*)d_in[2];
    const float* b1   = (const float*)d_in[3];
    const float* W2   = (const float*)d_in[4];
    const float* b2   = (const float*)d_in[5];
    const float* Wls1 = (const float*)d_in[6];
    const float* bls1 = (const float*)d_in[7];
    const float* wls2 = (const float*)d_in[8];
    const float* bls2 = (const float*)d_in[9];
    const float* Wlm1 = (const float*)d_in[10];
    const float* blm1 = (const float*)d_in[11];
    float* out = (float*)d_out;

    hipLaunchKernelGGL(lode_kernel, dim3(1), dim3(384), 0, stream,
                       x, dt, W1, b1, W2, b2, Wls1, bls1, wls2, bls2, Wlm1, blm1, out);
}

// Round 11
// 23046.567 us; speedup vs baseline: 1.9698x; 1.9698x over previous
//
#include <hip/hip_runtime.h>
#include <hip/hip_bf16.h>

#define T_STEPS 4096
#define HID 128
#define INP 8
#define MID 50
#define KSUB 10

__device__ __forceinline__ float rlane(float v, int i){
    // lane-uniform gather -> SGPR; usable directly as one FMA source operand
    return __int_as_float(__builtin_amdgcn_readlane(__float_as_int(v), i));
}

__device__ __forceinline__ float fast_tanh(float x){
    float e = __expf(2.0f * x);
    return 1.0f - 2.0f / (e + 1.0f);
}
__device__ __forceinline__ float softplus_f(float x){
    return (x > 20.0f) ? x : __logf(1.0f + __expf(x));
}

// lgkmcnt-only barrier: orders LDS ops, lets global loads stay in flight.
__device__ __forceinline__ void wg_barrier(){
    asm volatile("s_waitcnt lgkmcnt(0)\n\ts_barrier" ::: "memory");
}

// 6 waves (R9 structure + LDS-staged head weights + recurrence setprio):
//   waves 0-3 (4-way K-split): wave w owns z[32w..32w+32), register-resident
//     (lane l holds z[32w + (l&31)], replicated in lane pairs l, l+32).
//     phase A: 32 readlane + 32 FMA -> partial -> pbuf, ONE barrier,
//     4 conflict-free b32 reads -> lane l holds h1[l]. phase B: 50 readlane +
//     50 FMA (pair-redundant), update z. setprio(1): recurrence wins issue
//     arbitration against head waves on shared SIMDs.
//   waves 4-5: sigma/mu heads, lag-1, MONOLITHIC (R10's chunking regressed:
//     per-chunk global-load latency landed on the critical path 10x/step).
//     Head weights are staged into LDS once at start, so the head block has
//     no global-load latency and stays short.
__global__ __launch_bounds__(384, 2)
void lode_kernel(const float* __restrict__ x, const float* __restrict__ dt,
                 const float* __restrict__ W1, const float* __restrict__ b1,
                 const float* __restrict__ W2, const float* __restrict__ b2,
                 const float* __restrict__ Wls1, const float* __restrict__ bls1,
                 const float* __restrict__ wls2, const float* __restrict__ bls2,
                 const float* __restrict__ Wlm1, const float* __restrict__ blm1,
                 float* __restrict__ out)
{
    __shared__ __align__(16) float pbuf[2][4][64];   // [dbuf][wave][lane] partials
    __shared__ __align__(16) float zsnap[2][HID];    // per-step snapshot for heads
    __shared__ __align__(16) float WhL[2][HID*HID];  // staged Wls1 / Wlm1 (128 KB)

    const int tid = threadIdx.x;
    const int wid = tid >> 6;
    const int l   = tid & 63;

    // ---- stage head weights into LDS (all 384 threads, coalesced float4) ----
    {
        float4*       d0 = reinterpret_cast<float4*>(&WhL[0][0]);
        const float4* s0 = reinterpret_cast<const float4*>(Wls1);
        for (int i = tid; i < HID*HID/4; i += 384) d0[i] = s0[i];
        float4*       d1 = reinterpret_cast<float4*>(&WhL[1][0]);
        const float4* s1 = reinterpret_cast<const float4*>(Wlm1);
        for (int i = tid; i < HID*HID/4; i += 384) d1[i] = s1[i];
    }
    wg_barrier();   // publish staged weights (both branches execute this once)

    if (wid < 4){
        // ================= recurrence waves =================
        __builtin_amdgcn_s_setprio(1);          // win issue slots vs head waves
        const int base = wid << 5;              // z quarter start
        const int lc   = (l < MID) ? l : 0;     // clamped h1-output index

        // phase A weights: W1[base+i][lc], i = 0..31
        float w1h[32];
        #pragma unroll
        for (int i = 0; i < 32; ++i){
            const float v = W1[(base + i)*MID + lc];
            w1h[i] = (l < MID) ? v : 0.0f;
        }
        // x-part + bias: folded into wave 0's partial only
        float w1x[INP];
        #pragma unroll
        for (int j = 0; j < INP; ++j){
            const float v = W1[(HID + j)*MID + lc];
            w1x[j] = (wid == 0 && l < MID) ? v : 0.0f;
        }
        const float b1c = (wid == 0 && l < MID) ? b1[lc] : 0.0f;

        // phase B weights: full column W2[k][jc], k = 0..49
        const int jc = base + (l & 31);
        float w2c[MID];
        #pragma unroll
        for (int k = 0; k < MID; ++k) w2c[k] = W2[k*HID + jc];
        const float b2c = b2[jc];

        float zj = 0.0f;                         // z[jc], replicated pair-wise

        float4 xa  = *reinterpret_cast<const float4*>(&x[0]);
        float4 xb  = *reinterpret_cast<const float4*>(&x[4]);
        float2 dtc = *reinterpret_cast<const float2*>(&dt[0]);

        for (int t = 0; t < T_STEPS; ++t){
            const int tn = (t + 1 < T_STEPS) ? t + 1 : t;
            const float4 xan = *reinterpret_cast<const float4*>(&x[tn*INP]);
            const float4 xbn = *reinterpret_cast<const float4*>(&x[tn*INP + 4]);
            const float2 dtn = *reinterpret_cast<const float2*>(&dt[2*tn]);

            float xacc = b1c;                    // nonzero on wave 0 only
            xacc = fmaf(xa.x, w1x[0], xacc); xacc = fmaf(xa.y, w1x[1], xacc);
            xacc = fmaf(xa.z, w1x[2], xacc); xacc = fmaf(xa.w, w1x[3], xacc);
            xacc = fmaf(xb.x, w1x[4], xacc); xacc = fmaf(xb.y, w1x[5], xacc);
            xacc = fmaf(xb.z, w1x[6], xacc); xacc = fmaf(xb.w, w1x[7], xacc);
            const float hstep = (dtc.y - dtc.x) * (1.0f / KSUB);

            #pragma unroll 2
            for (int s = 0; s < KSUB; ++s){
                // ---- phase A: partial over own z quarter (registers only) ----
                float a0 = xacc, a1 = 0.0f, a2 = 0.0f, a3 = 0.0f;
                #pragma unroll
                for (int i = 0; i < 32; i += 4){
                    a0 = fmaf(rlane(zj, i+0), w1h[i+0], a0);
                    a1 = fmaf(rlane(zj, i+1), w1h[i+1], a1);
                    a2 = fmaf(rlane(zj, i+2), w1h[i+2], a2);
                    a3 = fmaf(rlane(zj, i+3), w1h[i+3], a3);
                }
                pbuf[s & 1][wid][l] = (a0 + a1) + (a2 + a3);
                wg_barrier();                   // the substep's ONE barrier

                // ---- combine partials: lane l -> h1[l] in register ----
                const float p0 = pbuf[s & 1][0][l];
                const float p1 = pbuf[s & 1][1][l];
                const float p2 = pbuf[s & 1][2][l];
                const float p3 = pbuf[s & 1][3][l];
                const float h1v = fast_tanh((p0 + p1) + (p2 + p3)); // 0 for l>=50

                // ---- phase B: full 50-dot via readlane (pair-redundant) ----
                float d0 = 0.0f, d1 = 0.0f, d2 = 0.0f, d3 = 0.0f;
                #pragma unroll
                for (int k = 0; k < 48; k += 4){
                    d0 = fmaf(rlane(h1v, k+0), w2c[k+0], d0);
                    d1 = fmaf(rlane(h1v, k+1), w2c[k+1], d1);
                    d2 = fmaf(rlane(h1v, k+2), w2c[k+2], d2);
                    d3 = fmaf(rlane(h1v, k+3), w2c[k+3], d3);
                }
                d0 = fmaf(rlane(h1v, 48), w2c[48], d0);
                d1 = fmaf(rlane(h1v, 49), w2c[49], d1);
                const float d = (d0 + d1) + (d2 + d3);
                zj += hstep * fast_tanh(b2c + d);
            }

            if (l < 32) zsnap[t & 1][base + l] = zj;   // publish for heads

            xa = xan; xb = xbn; dtc = dtn;
        }
        wg_barrier();                           // tail: publish step T-1 snapshot
    } else {
        // ======== head waves (4 = sigma, 5 = mu), lag 1 step, LDS weights ========
        const float* __restrict__ Wh = (wid == 4) ? &WhL[0][0] : &WhL[1][0];
        const float* __restrict__ bh = (wid == 4) ? bls1 : blm1;
        float2 bhp;   bhp.x = bh[2*l];     bhp.y = bh[2*l+1];
        float2 wls2p; wls2p.x = wls2[2*l]; wls2p.y = wls2[2*l+1];
        const float bls2s = bls2[0];

        for (int t = 0; t <= T_STEPS; ++t){
            if (t < T_STEPS){
                #pragma unroll 2
                for (int s = 0; s < KSUB; ++s) wg_barrier();   // match recurrence
            } else {
                wg_barrier();                   // matches recurrence tail barrier
            }
            if (t == 0) continue;
            const int ts = t - 1;               // emit output for step ts
            const float* zs = &zsnap[ts & 1][0];
            float px = bhp.x, py = bhp.y;
            #pragma unroll 4
            for (int k = 0; k < HID; k += 4){
                const float4 zv = *reinterpret_cast<const float4*>(&zs[k]);
                const float2 a0 = *reinterpret_cast<const float2*>(&Wh[(k+0)*HID + 2*l]);
                const float2 a1 = *reinterpret_cast<const float2*>(&Wh[(k+1)*HID + 2*l]);
                const float2 a2 = *reinterpret_cast<const float2*>(&Wh[(k+2)*HID + 2*l]);
                const float2 a3 = *reinterpret_cast<const float2*>(&Wh[(k+3)*HID + 2*l]);
                px = fmaf(zv.x, a0.x, px); py = fmaf(zv.x, a0.y, py);
                px = fmaf(zv.y, a1.x, px); py = fmaf(zv.y, a1.y, py);
                px = fmaf(zv.z, a2.x, px); py = fmaf(zv.z, a2.y, py);
                px = fmaf(zv.w, a3.x, px); py = fmaf(zv.w, a3.y, py);
            }
            px = fast_tanh(px); py = fast_tanh(py);
            float r = px*wls2p.x + py*wls2p.y;
            #pragma unroll
            for (int off = 1; off < 64; off <<= 1) r += __shfl_xor(r, off, 64);
            if (l == 0){
                if (wid == 4) out[T_STEPS + ts] = softplus_f(r + bls2s);  // sigma
                else          out[ts]           = r + bls2s;              // mu
            }
        }
    }
}

extern "C" void kernel_launch(void* const* d_in, const int* in_sizes, int n_in,
                              void* d_out, int out_size, void* d_ws, size_t ws_size,
                              hipStream_t stream)
{
    const float* x    = (const float*)d_in[0];
    const float* dt   = (const float*)d_in[1];
    const float* W1   = (const float*)d_in[2];
    const float* b1   = (const float*)d_in[3];
    const float* W2   = (const float*)d_in[4];
    const float* b2   = (const float*)d_in[5];
    const float* Wls1 = (const float*)d_in[6];
    const float* bls1 = (const float*)d_in[7];
    const float* wls2 = (const float*)d_in[8];
    const float* bls2 = (const float*)d_in[9];
    const float* Wlm1 = (const float*)d_in[10];
    const float* blm1 = (const float*)d_in[11];
    float* out = (float*)d_out;

    hipLaunchKernelGGL(lode_kernel, dim3(1), dim3(384), 0, stream,
                       x, dt, W1, b1, W2, b2, Wls1, bls1, wls2, bls2, Wlm1, blm1, out);
}

// Round 12
// 18483.313 us; speedup vs baseline: 2.4562x; 1.2469x over previous
//
#include <hip/hip_runtime.h>
#include <hip/hip_bf16.h>

#define T_STEPS 4096
#define HID 128
#define INP 8
#define MID 50
#define KSUB 10

typedef float v2f __attribute__((ext_vector_type(2)));

__device__ __forceinline__ v2f mk2(float a, float b){ v2f r; r.x = a; r.y = b; return r; }
__device__ __forceinline__ v2f bc2(float s){ v2f r; r.x = s; r.y = s; return r; }

__device__ __forceinline__ v2f fma2(v2f a, v2f b, v2f c){
#if __has_builtin(__builtin_elementwise_fma)
    return __builtin_elementwise_fma(a, b, c);
#else
    c.x = fmaf(a.x, b.x, c.x); c.y = fmaf(a.y, b.y, c.y); return c;
#endif
}

__device__ __forceinline__ float rlane(float v, int i){
    // lane-uniform gather -> SGPR; usable directly as one FMA source operand
    return __int_as_float(__builtin_amdgcn_readlane(__float_as_int(v), i));
}

__device__ __forceinline__ float fast_tanh(float x){
    float e = __expf(2.0f * x);
    return 1.0f - 2.0f / (e + 1.0f);
}
__device__ __forceinline__ float softplus_f(float x){
    return (x > 20.0f) ? x : __logf(1.0f + __expf(x));
}

// lgkmcnt-only barrier: orders LDS ops, lets global loads stay in flight.
__device__ __forceinline__ void wg_barrier(){
    asm volatile("s_waitcnt lgkmcnt(0)\n\ts_barrier" ::: "memory");
}

// 6 waves (R11 + chunked heads):
//   waves 0-3 (recurrence, 4-way K-split; UNCHANGED from R11): wave w owns
//     z[32w..32w+32) register-resident (lane l holds z[32w+(l&31)], pair-
//     replicated). Phase A: 32 readlane + 32 FMA -> partial -> pbuf, ONE
//     barrier, 4 b32 reads -> h1[l] register. Phase B: 50 readlane + 50 FMA.
//     setprio(1): recurrence wins issue arbitration on shared SIMDs.
//   waves 4-5 (sigma/mu heads, lag-1): head dot CHUNKED across the 10 substep
//     barrier windows (8 windows x 16 k of LDS-only reads ~70cyc each, then
//     reduce window, then store window). With weights in LDS (unlike R10's
//     failed chunking) each chunk has no global-load latency, so chunks are
//     absorbed into recurrence stall slots instead of delaying barriers.
__global__ __launch_bounds__(384, 2)
void lode_kernel(const float* __restrict__ x, const float* __restrict__ dt,
                 const float* __restrict__ W1, const float* __restrict__ b1,
                 const float* __restrict__ W2, const float* __restrict__ b2,
                 const float* __restrict__ Wls1, const float* __restrict__ bls1,
                 const float* __restrict__ wls2, const float* __restrict__ bls2,
                 const float* __restrict__ Wlm1, const float* __restrict__ blm1,
                 float* __restrict__ out)
{
    __shared__ __align__(16) float pbuf[2][4][64];   // [dbuf][wave][lane] partials
    __shared__ __align__(16) float zsnap[2][HID];    // per-step snapshot for heads
    __shared__ __align__(16) float WhL[2][HID*HID];  // staged Wls1 / Wlm1 (128 KB)

    const int tid = threadIdx.x;
    const int wid = tid >> 6;
    const int l   = tid & 63;

    // ---- stage head weights into LDS (all 384 threads, coalesced float4) ----
    {
        float4*       d0 = reinterpret_cast<float4*>(&WhL[0][0]);
        const float4* s0 = reinterpret_cast<const float4*>(Wls1);
        for (int i = tid; i < HID*HID/4; i += 384) d0[i] = s0[i];
        float4*       d1 = reinterpret_cast<float4*>(&WhL[1][0]);
        const float4* s1 = reinterpret_cast<const float4*>(Wlm1);
        for (int i = tid; i < HID*HID/4; i += 384) d1[i] = s1[i];
    }
    wg_barrier();   // publish staged weights (both branches execute this once)

    if (wid < 4){
        // ================= recurrence waves (unchanged from R11) =================
        __builtin_amdgcn_s_setprio(1);          // win issue slots vs head waves
        const int base = wid << 5;              // z quarter start
        const int lc   = (l < MID) ? l : 0;     // clamped h1-output index

        // phase A weights: W1[base+i][lc], i = 0..31
        float w1h[32];
        #pragma unroll
        for (int i = 0; i < 32; ++i){
            const float v = W1[(base + i)*MID + lc];
            w1h[i] = (l < MID) ? v : 0.0f;
        }
        // x-part + bias: folded into wave 0's partial only
        float w1x[INP];
        #pragma unroll
        for (int j = 0; j < INP; ++j){
            const float v = W1[(HID + j)*MID + lc];
            w1x[j] = (wid == 0 && l < MID) ? v : 0.0f;
        }
        const float b1c = (wid == 0 && l < MID) ? b1[lc] : 0.0f;

        // phase B weights: full column W2[k][jc], k = 0..49
        const int jc = base + (l & 31);
        float w2c[MID];
        #pragma unroll
        for (int k = 0; k < MID; ++k) w2c[k] = W2[k*HID + jc];
        const float b2c = b2[jc];

        float zj = 0.0f;                         // z[jc], replicated pair-wise

        float4 xa  = *reinterpret_cast<const float4*>(&x[0]);
        float4 xb  = *reinterpret_cast<const float4*>(&x[4]);
        float2 dtc = *reinterpret_cast<const float2*>(&dt[0]);

        for (int t = 0; t < T_STEPS; ++t){
            const int tn = (t + 1 < T_STEPS) ? t + 1 : t;
            const float4 xan = *reinterpret_cast<const float4*>(&x[tn*INP]);
            const float4 xbn = *reinterpret_cast<const float4*>(&x[tn*INP + 4]);
            const float2 dtn = *reinterpret_cast<const float2*>(&dt[2*tn]);

            float xacc = b1c;                    // nonzero on wave 0 only
            xacc = fmaf(xa.x, w1x[0], xacc); xacc = fmaf(xa.y, w1x[1], xacc);
            xacc = fmaf(xa.z, w1x[2], xacc); xacc = fmaf(xa.w, w1x[3], xacc);
            xacc = fmaf(xb.x, w1x[4], xacc); xacc = fmaf(xb.y, w1x[5], xacc);
            xacc = fmaf(xb.z, w1x[6], xacc); xacc = fmaf(xb.w, w1x[7], xacc);
            const float hstep = (dtc.y - dtc.x) * (1.0f / KSUB);

            #pragma unroll 2
            for (int s = 0; s < KSUB; ++s){
                // ---- phase A: partial over own z quarter (registers only) ----
                float a0 = xacc, a1 = 0.0f, a2 = 0.0f, a3 = 0.0f;
                #pragma unroll
                for (int i = 0; i < 32; i += 4){
                    a0 = fmaf(rlane(zj, i+0), w1h[i+0], a0);
                    a1 = fmaf(rlane(zj, i+1), w1h[i+1], a1);
                    a2 = fmaf(rlane(zj, i+2), w1h[i+2], a2);
                    a3 = fmaf(rlane(zj, i+3), w1h[i+3], a3);
                }
                pbuf[s & 1][wid][l] = (a0 + a1) + (a2 + a3);
                wg_barrier();                   // the substep's ONE barrier

                // ---- combine partials: lane l -> h1[l] in register ----
                const float p0 = pbuf[s & 1][0][l];
                const float p1 = pbuf[s & 1][1][l];
                const float p2 = pbuf[s & 1][2][l];
                const float p3 = pbuf[s & 1][3][l];
                const float h1v = fast_tanh((p0 + p1) + (p2 + p3)); // 0 for l>=50

                // ---- phase B: full 50-dot via readlane (pair-redundant) ----
                float d0 = 0.0f, d1 = 0.0f, d2 = 0.0f, d3 = 0.0f;
                #pragma unroll
                for (int k = 0; k < 48; k += 4){
                    d0 = fmaf(rlane(h1v, k+0), w2c[k+0], d0);
                    d1 = fmaf(rlane(h1v, k+1), w2c[k+1], d1);
                    d2 = fmaf(rlane(h1v, k+2), w2c[k+2], d2);
                    d3 = fmaf(rlane(h1v, k+3), w2c[k+3], d3);
                }
                d0 = fmaf(rlane(h1v, 48), w2c[48], d0);
                d1 = fmaf(rlane(h1v, 49), w2c[49], d1);
                const float d = (d0 + d1) + (d2 + d3);
                zj += hstep * fast_tanh(b2c + d);
            }

            if (l < 32) zsnap[t & 1][base + l] = zj;   // publish for heads

            xa = xan; xb = xbn; dtc = dtn;
        }
        wg_barrier();                           // tail: publish step T-1 snapshot
    } else {
        // ==== head waves (4 = sigma, 5 = mu), lag-1, CHUNKED over windows ====
        const float* __restrict__ Wh = (wid == 4) ? &WhL[0][0] : &WhL[1][0];
        const float* __restrict__ bh = (wid == 4) ? bls1 : blm1;
        const v2f bhp   = mk2(bh[2*l], bh[2*l+1]);
        const v2f wls2p = mk2(wls2[2*l], wls2[2*l+1]);
        const float bls2s = bls2[0];

        for (int t = 0; t < T_STEPS; ++t){
            v2f acc2 = bhp;                     // outputs (2l, 2l+1) accumulator
            float r = 0.0f;
            const float* zs = &zsnap[(t - 1) & 1][0];
            #pragma unroll
            for (int s = 0; s < KSUB; ++s){
                wg_barrier();                   // matches recurrence barrier s
                if (t == 0) continue;           // step -1 doesn't exist
                if (s < 8){
                    // 16 k's per window, LDS-only (no global latency in window)
                    #pragma unroll
                    for (int kk = 0; kk < 4; ++kk){
                        const int k = 16*s + 4*kk;
                        const float4 zv = *reinterpret_cast<const float4*>(&zs[k]);
                        const v2f w0 = *reinterpret_cast<const v2f*>(&Wh[(k+0)*HID + 2*l]);
                        const v2f w1 = *reinterpret_cast<const v2f*>(&Wh[(k+1)*HID + 2*l]);
                        const v2f w2 = *reinterpret_cast<const v2f*>(&Wh[(k+2)*HID + 2*l]);
                        const v2f w3 = *reinterpret_cast<const v2f*>(&Wh[(k+3)*HID + 2*l]);
                        acc2 = fma2(bc2(zv.x), w0, acc2);
                        acc2 = fma2(bc2(zv.y), w1, acc2);
                        acc2 = fma2(bc2(zv.z), w2, acc2);
                        acc2 = fma2(bc2(zv.w), w3, acc2);
                    }
                } else if (s == 8){
                    const float px = fast_tanh(acc2.x);
                    const float py = fast_tanh(acc2.y);
                    r = px*wls2p.x + py*wls2p.y;
                    #pragma unroll
                    for (int off = 1; off < 64; off <<= 1) r += __shfl_xor(r, off, 64);
                } else {
                    if (l == 0){
                        const int ts = t - 1;
                        if (wid == 4) out[T_STEPS + ts] = softplus_f(r + bls2s);
                        else          out[ts]           = r + bls2s;
                    }
                }
            }
        }
        wg_barrier();                           // matches recurrence tail barrier

        // final head for step T-1 (recurrence has exited; no contention)
        {
            const int ts = T_STEPS - 1;
            const float* zs = &zsnap[ts & 1][0];
            v2f acc2 = bhp;
            #pragma unroll 4
            for (int k = 0; k < HID; k += 4){
                const float4 zv = *reinterpret_cast<const float4*>(&zs[k]);
                const v2f w0 = *reinterpret_cast<const v2f*>(&Wh[(k+0)*HID + 2*l]);
                const v2f w1 = *reinterpret_cast<const v2f*>(&Wh[(k+1)*HID + 2*l]);
                const v2f w2 = *reinterpret_cast<const v2f*>(&Wh[(k+2)*HID + 2*l]);
                const v2f w3 = *reinterpret_cast<const v2f*>(&Wh[(k+3)*HID + 2*l]);
                acc2 = fma2(bc2(zv.x), w0, acc2);
                acc2 = fma2(bc2(zv.y), w1, acc2);
                acc2 = fma2(bc2(zv.z), w2, acc2);
                acc2 = fma2(bc2(zv.w), w3, acc2);
            }
            const float px = fast_tanh(acc2.x);
            const float py = fast_tanh(acc2.y);
            float r = px*wls2p.x + py*wls2p.y;
            #pragma unroll
            for (int off = 1; off < 64; off <<= 1) r += __shfl_xor(r, off, 64);
            if (l == 0){
                if (wid == 4) out[T_STEPS + ts] = softplus_f(r + bls2s);
                else          out[ts]           = r + bls2s;
            }
        }
    }
}

extern "C" void kernel_launch(void* const* d_in, const int* in_sizes, int n_in,
                              void* d_out, int out_size, void* d_ws, size_t ws_size,
                              hipStream_t stream)
{
    const float* x    = (const float*)d_in[0];
    const float* dt   = (const float*)d_in[1];
    const float* W1   = (const float*)d_in[2];
    const float* b1   = (const float*)d_in[3];
    const float* W2   = (const float*)d_in[4];
    const float* b2   = (const float*)d_in[5];
    const float* Wls1 = (const float*)d_in[6];
    const float* bls1 = (const float*)d_in[7];
    const float* wls2 = (const float*)d_in[8];
    const float* bls2 = (const float*)d_in[9];
    const float* Wlm1 = (const float*)d_in[10];
    const float* blm1 = (const float*)d_in[11];
    float* out = (float*)d_out;

    hipLaunchKernelGGL(lode_kernel, dim3(1), dim3(384), 0, stream,
                       x, dt, W1, b1, W2, b2, Wls1, bls1, wls2, bls2, Wlm1, blm1, out);
}